// Round 1
// baseline (203.172 us; speedup 1.0000x reference)
//
#include <hip/hip_runtime.h>

#define SLAB (256 * 256)

__global__ void init_acc_kernel(double* __restrict__ acc) {
    acc[threadIdx.x] = 0.0;
}

__global__ __launch_bounds__(256) void grad_loss_kernel(const float* __restrict__ x1,
                                                        const float* __restrict__ x2,
                                                        double* __restrict__ acc) {
    const int bid = blockIdx.x;        // 0 .. 254*254-1
    const int d = bid / 254 + 1;       // 1..254
    const int h = bid % 254 + 1;       // 1..254
    const int w = threadIdx.x;         // 0..255

    float val = 0.0f;
    if (w >= 1 && w <= 254) {
        const int idx = d * SLAB + h * 256 + w;

        float gw1 = x1[idx + SLAB] - x1[idx - SLAB];
        float gd1 = x1[idx + 256]  - x1[idx - 256];
        float gh1 = x1[idx + 1]    - x1[idx - 1];
        float m1  = sqrtf(gw1 * gw1 + gd1 * gd1 + gh1 * gh1 + 1e-6f);

        float gw2 = x2[idx + SLAB] - x2[idx - SLAB];
        float gd2 = x2[idx + 256]  - x2[idx - 256];
        float gh2 = x2[idx + 1]    - x2[idx - 1];
        float m2  = sqrtf(gw2 * gw2 + gd2 * gd2 + gh2 * gh2 + 1e-6f);

        // Edge-replication folded into integer weights:
        // interior coordinate 1 and 254 each absorb one padded border voxel.
        int wd = 1 + (d == 1) + (d == 254);
        int wh = 1 + (h == 1) + (h == 254);
        int ww = 1 + (w == 1) + (w == 254);
        val = fabsf(m1 - m2) * (float)(wd * wh * ww);
    }

    // wave-64 reduction
    for (int off = 32; off > 0; off >>= 1)
        val += __shfl_down(val, off, 64);

    __shared__ float smem[4];
    const int lane = threadIdx.x & 63;
    const int wid  = threadIdx.x >> 6;
    if (lane == 0) smem[wid] = val;
    __syncthreads();

    if (wid == 0) {
        float s = (lane < 4) ? smem[lane] : 0.0f;
        s += __shfl_down(s, 2, 64);
        s += __shfl_down(s, 1, 64);
        if (lane == 0)
            atomicAdd(&acc[blockIdx.x & 255], (double)s);
    }
}

__global__ void finalize_kernel(const double* __restrict__ acc, float* __restrict__ out) {
    double s = 0.0;
    for (int i = 0; i < 256; ++i) s += acc[i];
    out[0] = (float)(s / 16777216.0);   // mean over 256^3
}

extern "C" void kernel_launch(void* const* d_in, const int* in_sizes, int n_in,
                              void* d_out, int out_size, void* d_ws, size_t ws_size,
                              hipStream_t stream) {
    const float* x1 = (const float*)d_in[0];
    const float* x2 = (const float*)d_in[1];
    float* out = (float*)d_out;
    double* acc = (double*)d_ws;   // 256 doubles = 2 KiB of scratch

    init_acc_kernel<<<1, 256, 0, stream>>>(acc);
    grad_loss_kernel<<<254 * 254, 256, 0, stream>>>(x1, x2, acc);
    finalize_kernel<<<1, 1, 0, stream>>>(acc, out);
}

// Round 2
// 157.438 us; speedup vs baseline: 1.2905x; 1.2905x over previous
//
#include <hip/hip_runtime.h>

// x volumes: [256,256,256] fp32. Row (d,h) = 256 floats = 64 float4.
// float4-unit offsets: d*16384 + h*64 + lane.

__global__ void init_acc_kernel(double* __restrict__ acc) {
    acc[threadIdx.x] = 0.0;
}

__global__ __launch_bounds__(256) void grad_loss_kernel(const float4* __restrict__ x1,
                                                        const float4* __restrict__ x2,
                                                        double* __restrict__ acc) {
    const int tid   = threadIdx.x;
    const int lane  = tid & 63;     // w4 position within the row
    const int hslot = tid >> 6;     // wave id -> which h row of the 4-tile
    const int htile = blockIdx.x & 63;
    const int dchk  = blockIdx.x >> 6;

    const int h  = 1 + htile * 4 + hslot;   // 1..256 (mask >254)
    const int d0 = 1 + dchk * 16;           // 1,17,...,241

    // per-voxel w-axis weights (0 = excluded border voxel, 2 = edge-replicated)
    float ww0, ww1, ww2, ww3;
    {
        const int wbase = 4 * lane;
        ww0 = (wbase + 0 == 0)   ? 0.0f : ((wbase + 0 == 1)   ? 2.0f : 1.0f);
        ww1 = (wbase + 1 == 1)   ? 2.0f : 1.0f;
        ww2 = (wbase + 2 == 254) ? 2.0f : 1.0f;
        ww3 = (wbase + 3 == 255) ? 0.0f : ((wbase + 3 == 254) ? 2.0f : 1.0f);
    }

    float val = 0.0f;

    if (h <= 254) {
        const float whf = (h == 1 || h == 254) ? 2.0f : 1.0f;
        const int rowbase = h * 64 + lane;

        // rolling window along d: a = row(d-1), b = row(d), c = row(d+1)
        float4 a1 = x1[(d0 - 1) * 16384 + rowbase];
        float4 b1 = x1[d0 * 16384 + rowbase];
        float4 a2 = x2[(d0 - 1) * 16384 + rowbase];
        float4 b2 = x2[d0 * 16384 + rowbase];

        const int dend = (d0 + 16 <= 255) ? (d0 + 16) : 255;  // d <= 254
        for (int d = d0; d < dend; ++d) {
            const int base = d * 16384 + rowbase;
            float4 c1 = x1[base + 16384];
            float4 u1 = x1[base - 64];
            float4 v1 = x1[base + 64];
            float4 c2 = x2[base + 16384];
            float4 u2 = x2[base - 64];
            float4 v2 = x2[base + 64];

            // shifted w-neighbors of the center rows via cross-lane shuffle
            float l1 = __shfl_up(b1.w, 1, 64);
            float r1 = __shfl_down(b1.x, 1, 64);
            float l2 = __shfl_up(b2.w, 1, 64);
            float r2 = __shfl_down(b2.x, 1, 64);

            // voxel j=0..3 at w = 4*lane + j
            float gw, gd, gh, m10, m11, m12, m13, m20, m21, m22, m23;

            gw = c1.x - a1.x; gd = v1.x - u1.x; gh = b1.y - l1;
            m10 = sqrtf(gw * gw + gd * gd + gh * gh + 1e-6f);
            gw = c1.y - a1.y; gd = v1.y - u1.y; gh = b1.z - b1.x;
            m11 = sqrtf(gw * gw + gd * gd + gh * gh + 1e-6f);
            gw = c1.z - a1.z; gd = v1.z - u1.z; gh = b1.w - b1.y;
            m12 = sqrtf(gw * gw + gd * gd + gh * gh + 1e-6f);
            gw = c1.w - a1.w; gd = v1.w - u1.w; gh = r1 - b1.z;
            m13 = sqrtf(gw * gw + gd * gd + gh * gh + 1e-6f);

            gw = c2.x - a2.x; gd = v2.x - u2.x; gh = b2.y - l2;
            m20 = sqrtf(gw * gw + gd * gd + gh * gh + 1e-6f);
            gw = c2.y - a2.y; gd = v2.y - u2.y; gh = b2.z - b2.x;
            m21 = sqrtf(gw * gw + gd * gd + gh * gh + 1e-6f);
            gw = c2.z - a2.z; gd = v2.z - u2.z; gh = b2.w - b2.y;
            m22 = sqrtf(gw * gw + gd * gd + gh * gh + 1e-6f);
            gw = c2.w - a2.w; gd = v2.w - u2.w; gh = r2 - b2.z;
            m23 = sqrtf(gw * gw + gd * gd + gh * gh + 1e-6f);

            float inner = ww0 * fabsf(m10 - m20)
                        + ww1 * fabsf(m11 - m21)
                        + ww2 * fabsf(m12 - m22)
                        + ww3 * fabsf(m13 - m23);

            const float wdf = (d == 1 || d == 254) ? 2.0f : 1.0f;
            val += wdf * whf * inner;

            a1 = b1; b1 = c1;
            a2 = b2; b2 = c2;
        }
    }

    // wave-64 reduction
    for (int off = 32; off > 0; off >>= 1)
        val += __shfl_down(val, off, 64);

    __shared__ float smem[4];
    const int lid = tid & 63;
    const int wid = tid >> 6;
    if (lid == 0) smem[wid] = val;
    __syncthreads();

    if (wid == 0) {
        float s = (lid < 4) ? smem[lid] : 0.0f;
        s += __shfl_down(s, 2, 64);
        s += __shfl_down(s, 1, 64);
        if (lid == 0)
            atomicAdd(&acc[blockIdx.x & 255], (double)s);
    }
}

__global__ void finalize_kernel(const double* __restrict__ acc, float* __restrict__ out) {
    double v = acc[threadIdx.x];   // 256 threads, one slot each
    for (int off = 32; off > 0; off >>= 1)
        v += __shfl_down(v, off, 64);

    __shared__ double smem[4];
    const int lid = threadIdx.x & 63;
    const int wid = threadIdx.x >> 6;
    if (lid == 0) smem[wid] = v;
    __syncthreads();

    if (threadIdx.x == 0) {
        double s = smem[0] + smem[1] + smem[2] + smem[3];
        out[0] = (float)(s / 16777216.0);   // mean over 256^3
    }
}

extern "C" void kernel_launch(void* const* d_in, const int* in_sizes, int n_in,
                              void* d_out, int out_size, void* d_ws, size_t ws_size,
                              hipStream_t stream) {
    const float4* x1 = (const float4*)d_in[0];
    const float4* x2 = (const float4*)d_in[1];
    float* out = (float*)d_out;
    double* acc = (double*)d_ws;   // 256 doubles = 2 KiB scratch

    init_acc_kernel<<<1, 256, 0, stream>>>(acc);
    grad_loss_kernel<<<64 * 16, 256, 0, stream>>>(x1, x2, acc);
    finalize_kernel<<<1, 256, 0, stream>>>(acc, out);
}